// Round 13
// baseline (792.749 us; speedup 1.0000x reference)
//
#include <hip/hip_runtime.h>
#include <hip/hip_cooperative_groups.h>
#include <hip/hip_bf16.h>
#include <cstdint>

namespace cg = cooperative_groups;

#define DIN 16
#define HD  128
#define RNG 1024    // nodes per bin
#define LB  10      // log2(RNG)
#define GB  512     // grid blocks (2/CU -> co-resident for cooperative launch)
#define BT  256     // block threads
#define MAXB 128    // max bins (N <= 131072)

static __device__ __forceinline__ void fma4(float4& a, float s, const float4 v) {
    a.x = fmaf(s, v.x, a.x);
    a.y = fmaf(s, v.y, a.y);
    a.z = fmaf(s, v.z, a.z);
    a.w = fmaf(s, v.w, a.w);
}
static __device__ __forceinline__ void add4(float4& a, const float4 v) {
    a.x += v.x; a.y += v.y; a.z += v.z; a.w += v.w;
}

// Single cooperative kernel; phases separated by grid.sync().
extern "C" __global__ void __launch_bounds__(BT)
k_mega(const float* __restrict__ F,
       const int* __restrict__ src, const int* __restrict__ dst,
       const float* __restrict__ Win, const float* __restrict__ binp,
       const float* __restrict__ W1, const float* __restrict__ b1,
       const float* __restrict__ W2, const float* __restrict__ b2,
       const float* __restrict__ Wout, const float* __restrict__ bout,
       int* __restrict__ hist, int* __restrict__ ebin, int* __restrict__ ecsr,
       int* __restrict__ rowptr, float4* __restrict__ Y, float4* __restrict__ Ys,
       float4* __restrict__ Z1s, float* __restrict__ dinv,
       float* __restrict__ Wcp, float* __restrict__ cbuf, float* __restrict__ out,
       int N, int E, int R, int CHK, int T) {
    cg::grid_group grid = cg::this_grid();
    __shared__ __align__(16) char smem[11776];
    int tid = threadIdx.x;
    int bx = blockIdx.x;

    // ================= P0: bin histogram (all blocks) + weight fold (block 0) ==========
    {
        int* h = (int*)smem;
        for (int i = tid; i < R; i += BT) h[i] = 0;
        __syncthreads();
        int e0 = bx * CHK, e1 = e0 + CHK; if (e1 > E) e1 = E;
        for (int e = e0 + tid; e < e1; e += BT) atomicAdd(&h[dst[e] >> LB], 1);
        __syncthreads();
        for (int i = tid; i < R; i += BT) hist[i * GB + bx] = h[i];
        if (bx == 0) {
            __syncthreads();                 // h[] no longer needed
            float* sT = (float*)smem;        // 384 floats: T = W2 @ Wout
            for (int idx = tid; idx < HD * 3; idx += BT) {
                int k = idx / 3, o = idx - 3 * k;
                float s = 0.f;
                for (int j = 0; j < HD; j++) s = fmaf(W2[k * HD + j], Wout[j * 3 + o], s);
                sT[idx] = s;
            }
            if (tid < 3) {                   // b'' = Wout^T b2 + bout
                float s = bout[tid];
                for (int j = 0; j < HD; j++) s = fmaf(b2[j], Wout[j * 3 + tid], s);
                cbuf[3 + tid] = s;
            }
            __syncthreads();
            if (tid < 3) {                   // c1 = T^T b1
                float s = 0.f;
                for (int j = 0; j < HD; j++) s = fmaf(b1[j], sT[j * 3 + tid], s);
                cbuf[tid] = s;
            }
            for (int idx = tid; idx < HD * 3; idx += BT) {
                int k = idx / 3, o = idx - 3 * k;
                float s = 0.f;
                for (int j = 0; j < HD; j++) s = fmaf(W1[k * HD + j], sT[j * 3 + o], s);
                Wcp[k * 4 + o] = s;
            }
            for (int idx = tid; idx < HD; idx += BT) Wcp[idx * 4 + 3] = 0.f;
        }
    }
    __threadfence();
    grid.sync();

    // ================= P1: scan hist (block 0) || input MLP (blocks 1..GB-1) ===========
    if (bx == 0) {
        int nh = R * GB;
        int* sd = (int*)smem;
        int CH = (nh + BT - 1) / BT;
        int c0 = tid * CH, c1 = c0 + CH; if (c1 > nh) c1 = nh;
        int sum = 0;
        for (int i = c0; i < c1; i++) sum += hist[i];
        sd[tid] = sum;
        __syncthreads();
        for (int off = 1; off < BT; off <<= 1) {
            int t = (tid >= off) ? sd[tid - off] : 0;
            __syncthreads();
            sd[tid] += t;
            __syncthreads();
        }
        int base = sd[tid] - sum;
        for (int i = c0; i < c1; i++) { int t = hist[i]; hist[i] = base; base += t; }
    } else {
        struct MLP { float4 winT[512]; float4 wcT[128]; float4 bin4[32]; float sF[256]; };
        MLP* m = (MLP*)smem;
        for (int i = tid; i < 512; i += BT) {     // [k][c][l] transposed (conflict-free)
            int k = i >> 5, rem = i & 31, l = rem >> 1, c = rem & 1;
            m->winT[k * 32 + c * 16 + l] = ((const float4*)Win)[i];
        }
        for (int i = tid; i < 128; i += BT)
            m->wcT[(i & 7) * 16 + (i >> 3)] = ((const float4*)Wcp)[i];
        for (int i = tid; i < 32; i += BT) m->bin4[i] = ((const float4*)binp)[i];
        for (int t = bx - 1; t < T; t += GB - 1) {
            __syncthreads();
            int base = t * 16;
            {
                int node = base + (tid >> 4);
                m->sF[tid] = (node < N) ? F[(size_t)base * DIN + tid] : 0.f;
            }
            __syncthreads();
            int l = tid & 15, g = tid >> 4;
            int node = base + g;
            if (node < N) {                       // uniform per 16-lane group
                float4 h0 = m->bin4[l * 2 + 0];
                float4 h1 = m->bin4[l * 2 + 1];
                #pragma unroll
                for (int k = 0; k < DIN; k++) {
                    float f = m->sF[g * DIN + k];
                    fma4(h0, f, m->winT[k * 32 + l]);
                    fma4(h1, f, m->winT[k * 32 + 16 + l]);
                }
                h0.x = h0.x > 0.f ? h0.x : 0.01f * h0.x;
                h0.y = h0.y > 0.f ? h0.y : 0.01f * h0.y;
                h0.z = h0.z > 0.f ? h0.z : 0.01f * h0.z;
                h0.w = h0.w > 0.f ? h0.w : 0.01f * h0.w;
                h1.x = h1.x > 0.f ? h1.x : 0.01f * h1.x;
                h1.y = h1.y > 0.f ? h1.y : 0.01f * h1.y;
                h1.z = h1.z > 0.f ? h1.z : 0.01f * h1.z;
                h1.w = h1.w > 0.f ? h1.w : 0.01f * h1.w;
                float hv[8] = {h0.x, h0.y, h0.z, h0.w, h1.x, h1.y, h1.z, h1.w};
                float a0 = 0.f, a1 = 0.f, a2 = 0.f;
                #pragma unroll
                for (int jj = 0; jj < 8; jj++) {
                    float4 wc = m->wcT[jj * 16 + l];
                    a0 = fmaf(hv[jj], wc.x, a0);
                    a1 = fmaf(hv[jj], wc.y, a1);
                    a2 = fmaf(hv[jj], wc.z, a2);
                }
                #pragma unroll
                for (int off = 8; off > 0; off >>= 1) {
                    a0 += __shfl_down(a0, off, 16);
                    a1 += __shfl_down(a1, off, 16);
                    a2 += __shfl_down(a2, off, 16);
                }
                if (l == 0) Y[node] = make_float4(a0, a1, a2, 1.0f);
            }
        }
    }
    __threadfence();
    grid.sync();

    // ================= P2: deterministic partition (LDS cursors) =======================
    {
        int* cur = (int*)smem;
        for (int i = tid; i < R; i += BT) cur[i] = hist[i * GB + bx];
        __syncthreads();
        int e0 = bx * CHK, e1 = e0 + CHK; if (e1 > E) e1 = E;
        for (int e = e0 + tid; e < e1; e += BT) {
            int s = src[e], d = dst[e];
            int pos = atomicAdd(&cur[d >> LB], 1);
            ebin[pos] = (s << LB) | (d & (RNG - 1));
        }
    }
    __threadfence();
    grid.sync();

    // ================= P3: per-bin counting sort -> CSR + dinv + Ys ====================
    if (bx < R) {
        int* c = (int*)smem;                  // 1024 ints
        int* swv = (int*)(smem + 4096);       // 4 ints
        #pragma unroll
        for (int k = 0; k < 4; k++) c[tid + k * BT] = 0;
        __syncthreads();
        int e0 = hist[bx * GB];
        int e1 = (bx + 1 < R) ? hist[(bx + 1) * GB] : E;
        for (int e = e0 + tid; e < e1; e += BT) atomicAdd(&c[ebin[e] & (RNG - 1)], 1);
        __syncthreads();
        int v0 = c[4 * tid], v1 = c[4 * tid + 1], v2 = c[4 * tid + 2], v3 = c[4 * tid + 3];
        int ts = v0 + v1 + v2 + v3;
        int lane = tid & 63, wid = tid >> 6;
        int sc = ts;
        #pragma unroll
        for (int o = 1; o < 64; o <<= 1) {
            int t = __shfl_up(sc, o, 64);
            if (lane >= o) sc += t;
        }
        if (lane == 63) swv[wid] = sc;
        __syncthreads();
        if (tid == 0) {
            int acc = 0;
            #pragma unroll
            for (int i = 0; i < 4; i++) { int t = swv[i]; swv[i] = acc; acc += t; }
        }
        __syncthreads();
        int excl = sc - ts + swv[wid];
        int rp[4];
        rp[0] = e0 + excl; rp[1] = rp[0] + v0; rp[2] = rp[1] + v1; rp[3] = rp[2] + v2;
        int vv[4] = {v0, v1, v2, v3};
        int n0 = bx * RNG + 4 * tid;
        #pragma unroll
        for (int k = 0; k < 4; k++) {
            int n = n0 + k;
            if (n <= N) rowptr[n] = rp[k];    // n==N writes rowptr[N]==E (all dst < N)
            if (n < N) {
                float di = rsqrtf((float)vv[k] + 1.0f);
                dinv[n] = di;
                float4 y = Y[n];
                Ys[n] = make_float4(di * y.x, di * y.y, di * y.z, di);   // y.w == 1
            }
        }
        c[4 * tid] = rp[0]; c[4 * tid + 1] = rp[1];
        c[4 * tid + 2] = rp[2]; c[4 * tid + 3] = rp[3];
        __syncthreads();
        for (int e = e0 + tid; e < e1; e += BT) {
            int ed = ebin[e];
            int pos = atomicAdd(&c[ed & (RNG - 1)], 1);
            ecsr[pos] = ed >> LB;
        }
    } else if (bx == R) {
        if (tid < 16) ecsr[E + tid] = 0;      // slack for masked-12 gathers
    }
    __threadfence();
    grid.sync();

    // ================= P4: node-parallel agg A (masked-12 gather) ======================
    for (int n = bx * BT + tid; n < N; n += GB * BT) {
        int beg = rowptr[n], end = rowptr[n + 1];
        int deg = end - beg;
        float4 acc = Ys[n];
        int4 q0 = *(const int4*)(ecsr + beg);
        int4 q1 = *(const int4*)(ecsr + beg + 4);
        int4 q2 = *(const int4*)(ecsr + beg + 8);
        int si[12] = {q0.x, q0.y, q0.z, q0.w, q1.x, q1.y, q1.z, q1.w,
                      q2.x, q2.y, q2.z, q2.w};
        float4 g[12];
        #pragma unroll
        for (int k = 0; k < 12; k++) g[k] = Ys[si[k]];
        #pragma unroll
        for (int k = 0; k < 12; k++) if (k < deg) add4(acc, g[k]);
        for (int j = beg + 12; j < end; j++) add4(acc, Ys[ecsr[j]]);
        float di = dinv[n];
        float d2 = di * di;
        Z1s[n] = make_float4(d2 * acc.x, d2 * acc.y, d2 * acc.z, d2 * acc.w);
    }
    __threadfence();
    grid.sync();

    // ================= P5: node-parallel agg B + epilogue ==============================
    for (int n = bx * BT + tid; n < N; n += GB * BT) {
        int beg = rowptr[n], end = rowptr[n + 1];
        int deg = end - beg;
        float4 acc = Z1s[n];
        float di = dinv[n];
        float r = acc.w / di;                 // (Ahat*1)[n]
        int4 q0 = *(const int4*)(ecsr + beg);
        int4 q1 = *(const int4*)(ecsr + beg + 4);
        int4 q2 = *(const int4*)(ecsr + beg + 8);
        int si[12] = {q0.x, q0.y, q0.z, q0.w, q1.x, q1.y, q1.z, q1.w,
                      q2.x, q2.y, q2.z, q2.w};
        float4 g[12];
        #pragma unroll
        for (int k = 0; k < 12; k++) g[k] = Z1s[si[k]];
        #pragma unroll
        for (int k = 0; k < 12; k++) if (k < deg) add4(acc, g[k]);
        for (int j = beg + 12; j < end; j++) add4(acc, Z1s[ecsr[j]]);
        out[(size_t)n * 3 + 0] = di * acc.x + r * cbuf[0] + cbuf[3];
        out[(size_t)n * 3 + 1] = di * acc.y + r * cbuf[1] + cbuf[4];
        out[(size_t)n * 3 + 2] = di * acc.z + r * cbuf[2] + cbuf[5];
    }
}

extern "C" void kernel_launch(void* const* d_in, const int* in_sizes, int n_in,
                              void* d_out, int out_size, void* d_ws, size_t ws_size,
                              hipStream_t stream) {
    const float* feat = (const float*)d_in[0];
    const int*   ei   = (const int*)d_in[1];
    // d_in[2] edge_type: unused (as in reference)
    const float* Win  = (const float*)d_in[3];
    const float* binp = (const float*)d_in[4];
    const float* W1   = (const float*)d_in[5];
    const float* b1   = (const float*)d_in[6];
    const float* W2   = (const float*)d_in[7];
    const float* b2   = (const float*)d_in[8];
    const float* Wout = (const float*)d_in[9];
    const float* bout = (const float*)d_in[10];
    float* out = (float*)d_out;

    int N = in_sizes[0] / DIN;
    int E = in_sizes[2];
    const int* src = ei;
    const int* dst = ei + E;

    int R = (N + RNG - 1) >> LB;            // 98 for N=100k (must be <= MAXB)
    int CHK = (E + GB - 1) / GB;            // edges per block chunk
    int NH = R * GB;
    int T = (N + 15) / 16;                  // MLP tiles

    char* p = (char*)d_ws;
    auto alloc = [&](size_t bytes) -> char* {
        char* q = p;
        p += (bytes + 511) & ~(size_t)511;
        return q;
    };
    int*    hist   = (int*)alloc((size_t)NH * 4);
    int*    ebin   = (int*)alloc((size_t)E * 4);
    int*    ecsr   = (int*)alloc(((size_t)E + 16) * 4);
    int*    rowptr = (int*)alloc((size_t)(N + 1) * 4);
    float4* Y      = (float4*)alloc((size_t)N * 16);
    float4* Ys     = (float4*)alloc((size_t)N * 16);
    float4* Z1s    = (float4*)alloc((size_t)N * 16);
    float*  dinv   = (float*)alloc((size_t)N * 4);
    float*  Wcp    = (float*)alloc(HD * 4 * 4);
    float*  cbuf   = (float*)alloc(8 * 4);

    void* args[] = {
        (void*)&feat, (void*)&src, (void*)&dst, (void*)&Win, (void*)&binp,
        (void*)&W1, (void*)&b1, (void*)&W2, (void*)&b2, (void*)&Wout, (void*)&bout,
        (void*)&hist, (void*)&ebin, (void*)&ecsr, (void*)&rowptr,
        (void*)&Y, (void*)&Ys, (void*)&Z1s, (void*)&dinv,
        (void*)&Wcp, (void*)&cbuf, (void*)&out,
        (void*)&N, (void*)&E, (void*)&R, (void*)&CHK, (void*)&T
    };
    hipLaunchCooperativeKernel((void*)k_mega, dim3(GB), dim3(BT), args, 0, stream);
}

// Round 14
// 155.508 us; speedup vs baseline: 5.0978x; 5.0978x over previous
//
#include <hip/hip_runtime.h>
#include <hip/hip_bf16.h>
#include <cstdint>

#define DIN 16
#define HD  128
#define RNG 2048    // nodes per bin
#define LB  11      // log2(RNG)
#define MAXB 64     // max bins (N <= 131072; src fits 32-LB = 21 bits)
#define PB  256     // partition/hist blocks

static __device__ __forceinline__ void fma4(float4& a, float s, const float4 v) {
    a.x = fmaf(s, v.x, a.x);
    a.y = fmaf(s, v.y, a.y);
    a.z = fmaf(s, v.z, a.z);
    a.w = fmaf(s, v.w, a.w);
}
static __device__ __forceinline__ void add4(float4& a, const float4 v) {
    a.x += v.x; a.y += v.y; a.z += v.z; a.w += v.w;
}
static __device__ __forceinline__ void lrelu4(float4& h) {
    h.x = h.x > 0.f ? h.x : 0.01f * h.x;
    h.y = h.y > 0.f ? h.y : 0.01f * h.y;
    h.z = h.z > 0.f ? h.z : 0.01f * h.z;
    h.w = h.w > 0.f ? h.w : 0.01f * h.w;
}

// ---------------- dispatch 1: blocks [0,PB) bin-histogram; block PB folds weights -------
__global__ __launch_bounds__(256) void k_histfold(const int* __restrict__ dst,
                                                  int* __restrict__ hist,
                                                  int E, int R, int CHK,
                                                  const float* __restrict__ W1,
                                                  const float* __restrict__ b1,
                                                  const float* __restrict__ W2,
                                                  const float* __restrict__ b2,
                                                  const float* __restrict__ Wout,
                                                  const float* __restrict__ bout,
                                                  float* __restrict__ Wcp,
                                                  float* __restrict__ cbuf) {
    int tid = threadIdx.x;
    if (blockIdx.x < PB) {
        __shared__ int h[MAXB];
        for (int i = tid; i < R; i += 256) h[i] = 0;
        __syncthreads();
        int e0 = blockIdx.x * CHK;
        int e1 = e0 + CHK; if (e1 > E) e1 = E;
        for (int e = e0 + tid; e < e1; e += 256) atomicAdd(&h[dst[e] >> LB], 1);
        __syncthreads();
        for (int i = tid; i < R; i += 256) hist[i * PB + blockIdx.x] = h[i];
        return;
    }
    // weight folding: Wc = W1@W2@Wout, c1 = (W2@Wout)^T b1, b'' = Wout^T b2 + bout
    __shared__ float sT[HD * 3];
    for (int idx = tid; idx < HD * 3; idx += 256) {
        int k = idx / 3, o = idx - 3 * k;
        float s = 0.f;
        for (int j = 0; j < HD; j++) s = fmaf(W2[k * HD + j], Wout[j * 3 + o], s);
        sT[idx] = s;
    }
    if (tid < 3) {
        float s = bout[tid];
        for (int j = 0; j < HD; j++) s = fmaf(b2[j], Wout[j * 3 + tid], s);
        cbuf[3 + tid] = s;
    }
    __syncthreads();
    if (tid < 3) {
        float s = 0.f;
        for (int j = 0; j < HD; j++) s = fmaf(b1[j], sT[j * 3 + tid], s);
        cbuf[tid] = s;
    }
    for (int idx = tid; idx < HD * 3; idx += 256) {
        int k = idx / 3, o = idx - 3 * k;
        float s = 0.f;
        for (int j = 0; j < HD; j++) s = fmaf(W1[k * HD + j], sT[j * 3 + o], s);
        Wcp[k * 4 + o] = s;
    }
    for (int idx = tid; idx < HD; idx += 256) Wcp[idx * 4 + 3] = 0.f;
}

// ---------------- dispatch 2: block 0 scans hist; blocks 1.. run input MLP --------------
// 2 nodes per 16-lane group: every LDS weight read amortized over two nodes.
__global__ __launch_bounds__(1024) void k_scanmlp(int* __restrict__ hist, int nh,
                                                  const float* __restrict__ F,
                                                  const float* __restrict__ Win,
                                                  const float* __restrict__ bin,
                                                  const float4* __restrict__ Wcp,
                                                  float4* __restrict__ Y, int N) {
    int tid = threadIdx.x;
    if (blockIdx.x == 0) {
        __shared__ int sd[1024];
        int CH = (nh + 1023) / 1024;
        int c0 = tid * CH;
        int c1 = c0 + CH; if (c1 > nh) c1 = nh;
        int sum = 0;
        for (int i = c0; i < c1; i++) sum += hist[i];
        sd[tid] = sum;
        __syncthreads();
        for (int off = 1; off < 1024; off <<= 1) {
            int t = (tid >= off) ? sd[tid - off] : 0;
            __syncthreads();
            sd[tid] += t;
            __syncthreads();
        }
        int base = sd[tid] - sum;
        for (int i = c0; i < c1; i++) { int t = hist[i]; hist[i] = base; base += t; }
        return;
    }
    __shared__ float4 sWinT[DIN * HD / 4];  // [k][c][l] : idx = k*32 + c*16 + l (8 KB)
    __shared__ float4 sWcT[HD];             // [jj][l]   : idx = jj*16 + l        (2 KB)
    __shared__ float4 sBin[HD / 4];
    __shared__ float  sF[128 * DIN];        // 8 KB: 128 nodes per block
    if (tid < DIN * HD / 4) {               // 512 float4
        int k = tid >> 5, rem = tid & 31, l = rem >> 1, c = rem & 1;
        sWinT[k * 32 + c * 16 + l] = ((const float4*)Win)[tid];
    } else if (tid < DIN * HD / 4 + HD) {   // 128 float4
        int i = tid - DIN * HD / 4;
        sWcT[(i & 7) * 16 + (i >> 3)] = Wcp[i];
    } else if (tid < DIN * HD / 4 + HD + HD / 4) {
        int i = tid - DIN * HD / 4 - HD;
        sBin[i] = ((const float4*)bin)[i];
    }
    int base = (blockIdx.x - 1) * 128;
    {
        int n0 = base + (tid >> 4);
        sF[tid] = (n0 < N) ? F[(size_t)base * DIN + tid] : 0.f;
        int n1 = base + ((tid + 1024) >> 4);
        sF[tid + 1024] = (n1 < N) ? F[(size_t)base * DIN + tid + 1024] : 0.f;
    }
    __syncthreads();
    int l = tid & 15;        // lane owns hidden features 8l..8l+7
    int g = tid >> 4;        // group handles nodes base+2g, base+2g+1
    int nodeA = base + 2 * g;
    int nodeB = nodeA + 1;
    if (nodeA >= N) return;
    float4 a0 = sBin[l * 2 + 0], a1 = sBin[l * 2 + 1];
    float4 b0 = a0, b1 = a1;
    #pragma unroll
    for (int k = 0; k < DIN; k++) {
        float4 w0 = sWinT[k * 32 + l];
        float4 w1 = sWinT[k * 32 + 16 + l];
        float fA = sF[(2 * g) * DIN + k];
        float fB = sF[(2 * g + 1) * DIN + k];
        fma4(a0, fA, w0); fma4(a1, fA, w1);
        fma4(b0, fB, w0); fma4(b1, fB, w1);
    }
    lrelu4(a0); lrelu4(a1); lrelu4(b0); lrelu4(b1);
    float hA[8] = {a0.x, a0.y, a0.z, a0.w, a1.x, a1.y, a1.z, a1.w};
    float hB[8] = {b0.x, b0.y, b0.z, b0.w, b1.x, b1.y, b1.z, b1.w};
    float pA0 = 0.f, pA1 = 0.f, pA2 = 0.f, pB0 = 0.f, pB1 = 0.f, pB2 = 0.f;
    #pragma unroll
    for (int jj = 0; jj < 8; jj++) {
        float4 wc = sWcT[jj * 16 + l];
        pA0 = fmaf(hA[jj], wc.x, pA0);
        pA1 = fmaf(hA[jj], wc.y, pA1);
        pA2 = fmaf(hA[jj], wc.z, pA2);
        pB0 = fmaf(hB[jj], wc.x, pB0);
        pB1 = fmaf(hB[jj], wc.y, pB1);
        pB2 = fmaf(hB[jj], wc.z, pB2);
    }
    #pragma unroll
    for (int off = 8; off > 0; off >>= 1) {
        pA0 += __shfl_down(pA0, off, 16);
        pA1 += __shfl_down(pA1, off, 16);
        pA2 += __shfl_down(pA2, off, 16);
        pB0 += __shfl_down(pB0, off, 16);
        pB1 += __shfl_down(pB1, off, 16);
        pB2 += __shfl_down(pB2, off, 16);
    }
    if (l == 0) {
        Y[nodeA] = make_float4(pA0, pA1, pA2, 1.0f);
        if (nodeB < N) Y[nodeB] = make_float4(pB0, pB1, pB2, 1.0f);
    }
}

// ---------------- dispatch 3: deterministic partition, packed 4 B/edge ----------------
__global__ __launch_bounds__(256) void k_part(const int* __restrict__ src,
                                              const int* __restrict__ dst,
                                              const int* __restrict__ off,
                                              int* __restrict__ ebin,
                                              int E, int R, int CHK) {
    __shared__ int cur[MAXB];
    int tid = threadIdx.x;
    int b = blockIdx.x;
    for (int i = tid; i < R; i += 256) cur[i] = off[i * PB + b];
    __syncthreads();
    int e0 = b * CHK;
    int e1 = e0 + CHK; if (e1 > E) e1 = E;
    for (int e = e0 + tid; e < e1; e += 256) {
        int s = src[e], d = dst[e];
        int pos = atomicAdd(&cur[d >> LB], 1);     // LDS atomic
        ebin[pos] = (s << LB) | (d & (RNG - 1));
    }
}

// ---------------- dispatch 4: per-bin counting sort -> CSR + dinv + Ys ----------------
__global__ __launch_bounds__(1024) void k_csr(const int* __restrict__ ebin,
                                              const int* __restrict__ off,
                                              const float4* __restrict__ Y,
                                              int* __restrict__ rowptr,
                                              int* __restrict__ ecsr,
                                              float* __restrict__ dinv,
                                              float4* __restrict__ Ys,
                                              int N, int E, int R) {
    __shared__ int c[RNG];      // counts -> cursors
    __shared__ int swv[16];
    int tid = threadIdx.x;
    int b = blockIdx.x;
    c[tid] = 0; c[tid + 1024] = 0;
    __syncthreads();
    int e0 = off[b * PB];
    int e1 = (b + 1 < R) ? off[(b + 1) * PB] : E;
    for (int e = e0 + tid; e < e1; e += 1024) atomicAdd(&c[ebin[e] & (RNG - 1)], 1);
    __syncthreads();
    int v0 = c[2 * tid], v1 = c[2 * tid + 1];
    int ts = v0 + v1;
    int lane = tid & 63, wid = tid >> 6;
    int sc = ts;                             // wave-inclusive scan
    #pragma unroll
    for (int o = 1; o < 64; o <<= 1) {
        int t = __shfl_up(sc, o, 64);
        if (lane >= o) sc += t;
    }
    if (lane == 63) swv[wid] = sc;
    __syncthreads();
    if (tid < 16) {                          // 16-wave offset scan (exclusive)
        int v = swv[tid];
        int s2 = v;
        #pragma unroll
        for (int o = 1; o < 16; o <<= 1) {
            int t = __shfl_up(s2, o, 16);
            if (tid >= o) s2 += t;
        }
        swv[tid] = s2 - v;
    }
    __syncthreads();
    int excl = sc - ts + swv[wid];
    int rp0 = e0 + excl;                     // global CSR start of node b*RNG+2*tid
    int rp1 = rp0 + v0;
    int n0 = b * RNG + 2 * tid;
    if (n0 <= N) rowptr[n0] = rp0;
    if (n0 + 1 <= N) rowptr[n0 + 1] = rp1;
    if (b == R - 1 && tid == 1023) rowptr[N] = E;
    if (n0 < N) {
        float di = rsqrtf((float)v0 + 1.0f);
        dinv[n0] = di;
        float4 y = Y[n0];
        Ys[n0] = make_float4(di * y.x, di * y.y, di * y.z, di);   // y.w == 1
    }
    if (n0 + 1 < N) {
        float di = rsqrtf((float)v1 + 1.0f);
        dinv[n0 + 1] = di;
        float4 y = Y[n0 + 1];
        Ys[n0 + 1] = make_float4(di * y.x, di * y.y, di * y.z, di);
    }
    c[2 * tid] = rp0;                        // cursors
    c[2 * tid + 1] = rp1;
    __syncthreads();
    for (int e = e0 + tid; e < e1; e += 1024) {
        int ed = ebin[e];
        int pos = atomicAdd(&c[ed & (RNG - 1)], 1);    // LDS atomic
        ecsr[pos] = ed >> LB;
    }
    if (b == 0 && tid < 16) ecsr[E + tid] = 0;   // slack for masked-12 gathers
}

// ---------------- dispatch 5: node-parallel agg A with masked-12 gather ----------------
__global__ __launch_bounds__(256) void k_aggA(const int* __restrict__ rowptr,
                                              const int* __restrict__ ecsr,
                                              const float4* __restrict__ Ys,
                                              const float* __restrict__ dinv,
                                              float4* __restrict__ Z1s, int N) {
    int n = blockIdx.x * blockDim.x + threadIdx.x;
    if (n >= N) return;
    int beg = rowptr[n], end = rowptr[n + 1];
    int deg = end - beg;
    float4 acc = Ys[n];
    int4 q0 = *(const int4*)(ecsr + beg);
    int4 q1 = *(const int4*)(ecsr + beg + 4);
    int4 q2 = *(const int4*)(ecsr + beg + 8);
    int si[12] = {q0.x, q0.y, q0.z, q0.w, q1.x, q1.y, q1.z, q1.w,
                  q2.x, q2.y, q2.z, q2.w};
    float4 g[12];
    #pragma unroll
    for (int k = 0; k < 12; k++) g[k] = Ys[si[k]];   // 12 independent gathers in flight
    #pragma unroll
    for (int k = 0; k < 12; k++) if (k < deg) add4(acc, g[k]);
    for (int j = beg + 12; j < end; j++) add4(acc, Ys[ecsr[j]]);   // rare tail (deg>12)
    float di = dinv[n];
    float d2 = di * di;
    Z1s[n] = make_float4(d2 * acc.x, d2 * acc.y, d2 * acc.z, d2 * acc.w);
}

// ---------------- dispatch 6: node-parallel agg B + epilogue ----------------
__global__ __launch_bounds__(256) void k_aggB(const int* __restrict__ rowptr,
                                              const int* __restrict__ ecsr,
                                              const float4* __restrict__ Z1s,
                                              const float* __restrict__ dinv,
                                              const float* __restrict__ cbuf,
                                              float* __restrict__ out, int N) {
    int n = blockIdx.x * blockDim.x + threadIdx.x;
    if (n >= N) return;
    int beg = rowptr[n], end = rowptr[n + 1];
    int deg = end - beg;
    float4 acc = Z1s[n];
    float di = dinv[n];
    float r = acc.w / di;                   // (Ahat*1)[n]
    int4 q0 = *(const int4*)(ecsr + beg);
    int4 q1 = *(const int4*)(ecsr + beg + 4);
    int4 q2 = *(const int4*)(ecsr + beg + 8);
    int si[12] = {q0.x, q0.y, q0.z, q0.w, q1.x, q1.y, q1.z, q1.w,
                  q2.x, q2.y, q2.z, q2.w};
    float4 g[12];
    #pragma unroll
    for (int k = 0; k < 12; k++) g[k] = Z1s[si[k]];
    #pragma unroll
    for (int k = 0; k < 12; k++) if (k < deg) add4(acc, g[k]);
    for (int j = beg + 12; j < end; j++) add4(acc, Z1s[ecsr[j]]);
    out[(size_t)n * 3 + 0] = di * acc.x + r * cbuf[0] + cbuf[3];
    out[(size_t)n * 3 + 1] = di * acc.y + r * cbuf[1] + cbuf[4];
    out[(size_t)n * 3 + 2] = di * acc.z + r * cbuf[2] + cbuf[5];
}

extern "C" void kernel_launch(void* const* d_in, const int* in_sizes, int n_in,
                              void* d_out, int out_size, void* d_ws, size_t ws_size,
                              hipStream_t stream) {
    const float* feat = (const float*)d_in[0];
    const int*   ei   = (const int*)d_in[1];
    // d_in[2] edge_type: unused (as in reference)
    const float* Win  = (const float*)d_in[3];
    const float* bin  = (const float*)d_in[4];
    const float* W1   = (const float*)d_in[5];
    const float* b1   = (const float*)d_in[6];
    const float* W2   = (const float*)d_in[7];
    const float* b2   = (const float*)d_in[8];
    const float* Wout = (const float*)d_in[9];
    const float* bout = (const float*)d_in[10];
    float* out = (float*)d_out;

    int N = in_sizes[0] / DIN;
    int E = in_sizes[2];
    const int* src = ei;
    const int* dst = ei + E;

    int R = (N + RNG - 1) >> LB;            // 49 for N=100k
    int CHK = (E + PB - 1) / PB;            // edges per hist/part block
    int NH = R * PB;
    int XB = (N + 127) / 128;               // MLP blocks (128 nodes per 1024-thr block)

    char* p = (char*)d_ws;
    auto alloc = [&](size_t bytes) -> char* {
        char* q = p;
        p += (bytes + 511) & ~(size_t)511;
        return q;
    };
    int*    hist   = (int*)alloc((size_t)NH * 4);
    int*    ebin   = (int*)alloc((size_t)E * 4);          // 3.2 MB (packed)
    int*    ecsr   = (int*)alloc(((size_t)E + 16) * 4);   // 3.2 MB + slack
    int*    rowptr = (int*)alloc((size_t)(N + 1) * 4);
    float4* Y      = (float4*)alloc((size_t)N * 16);
    float4* Ys     = (float4*)alloc((size_t)N * 16);
    float4* Z1s    = (float4*)alloc((size_t)N * 16);
    float*  dinv   = (float*)alloc((size_t)N * 4);
    float*  Wcp    = (float*)alloc(HD * 4 * 4);
    float*  cbuf   = (float*)alloc(8 * 4);

    k_histfold<<<PB + 1, 256, 0, stream>>>(dst, hist, E, R, CHK,
                                           W1, b1, W2, b2, Wout, bout, Wcp, cbuf);
    k_scanmlp<<<1 + XB, 1024, 0, stream>>>(hist, NH, feat, Win, bin,
                                           (const float4*)Wcp, Y, N);
    k_part<<<PB, 256, 0, stream>>>(src, dst, hist, ebin, E, R, CHK);
    k_csr<<<R, 1024, 0, stream>>>(ebin, hist, Y, rowptr, ecsr, dinv, Ys, N, E, R);
    k_aggA<<<(N + 255) / 256, 256, 0, stream>>>(rowptr, ecsr, Ys, dinv, Z1s, N);
    k_aggB<<<(N + 255) / 256, 256, 0, stream>>>(rowptr, ecsr, Z1s, dinv, cbuf, out, N);
}